// Round 7
// baseline (669.691 us; speedup 1.0000x reference)
//
#include <hip/hip_runtime.h>
#include <math.h>

// Problem constants (ConformerEncoderLayer, T=512 B=16 C=512 H=8 d=64 DFF=2048 K=31)
#define T_SEQ 512
#define B_SZ  16
#define C_DIM 512
#define NH    8
#define HD    64
#define DFF_  2048
#define NROWS (T_SEQ * B_SZ)   // 8192 rows of (t*B+b)
#define BCHUNK 4               // attention batches per chunk (32 bh per chunk)
#define EPS_BN 1.2840254166877414f  // exp(0.25)

typedef unsigned short u16;
typedef __attribute__((ext_vector_type(8))) short bf16x8;
typedef __attribute__((ext_vector_type(4))) float f32x4;

__device__ __forceinline__ float sigmoidf_(float x) { return 1.f / (1.f + __expf(-x)); }
__device__ __forceinline__ float dswishf_(float x)  { return x * sigmoidf_(x - 1.f); }
__device__ __forceinline__ float clampd_(float x)   { return fminf(fmaxf(x, -1e4f), 1e4f); }
__device__ __forceinline__ u16 f2bf_(float x) {
    unsigned u = __float_as_uint(x);
    return (u16)((u + 0x7fffu + ((u >> 16) & 1u)) >> 16);
}
__device__ __forceinline__ float bf2f_(u16 u) {
    return __uint_as_float(((unsigned)u) << 16);
}

// ---------------------------------------------------------------------------
// bf16 MFMA GEMM, double-buffered LDS (R7): out = [res +] act(A@W^T + b)
// 128x128 tile, BK=32, 4 waves (2x2 of 64x64). Prefetch next K-tile into regs
// during MFMA; ONE barrier per K-iter (writes go to the alternate buffer;
// prior-iter barrier guarantees all reads of that buffer completed).
// N, M multiples of 128; K multiple of 32 (>=64).
// ---------------------------------------------------------------------------
template <int ACT, bool HAS_RES, bool O32, bool O16>
__global__ __launch_bounds__(256) void gemm_mfma(
    const u16* __restrict__ A, const u16* __restrict__ W,
    const float* __restrict__ bias, const float* __restrict__ res,
    float* __restrict__ out32, u16* __restrict__ out16, int N, int K, int M)
{
    __shared__ __align__(16) u16 As[2][128 * 32];
    __shared__ __align__(16) u16 Bs[2][128 * 32];
    const int tid  = threadIdx.x;
    const int wv   = tid >> 6;
    const int lane = tid & 63;
    const int wm   = wv >> 1, wn = wv & 1;
    const int m0 = blockIdx.x * 128;
    const int n0 = blockIdx.y * 128;

    const int sc_ = tid & 3;
    const int sr_ = tid >> 2;
    const u16* gA = A + (size_t)(n0 + sr_) * K + sc_ * 8;
    const u16* gB = W + (size_t)(m0 + sr_) * K + sc_ * 8;
    const int ls = sr_ * 32 + sc_ * 8;
    const size_t rowK64 = (size_t)64 * K;

    f32x4 acc[4][4];
#pragma unroll
    for (int i = 0; i < 4; ++i)
#pragma unroll
        for (int j = 0; j < 4; ++j) acc[i][j] = (f32x4)0.f;

    const int frow = (lane & 15);
    const int fk   = (lane >> 4) * 8;

    uint4 ra0 = *(const uint4*)(gA);
    uint4 ra1 = *(const uint4*)(gA + rowK64);
    uint4 rb0 = *(const uint4*)(gB);
    uint4 rb1 = *(const uint4*)(gB + rowK64);
    *(uint4*)&As[0][ls] = ra0; *(uint4*)&As[0][2048 + ls] = ra1;
    *(uint4*)&Bs[0][ls] = rb0; *(uint4*)&Bs[0][2048 + ls] = rb1;
    __syncthreads();

    int buf = 0;
    for (int k0 = 0; k0 < K; k0 += 32) {
        const bool last = (k0 + 32 >= K);
        if (!last) {
            ra0 = *(const uint4*)(gA + k0 + 32);
            ra1 = *(const uint4*)(gA + k0 + 32 + rowK64);
            rb0 = *(const uint4*)(gB + k0 + 32);
            rb1 = *(const uint4*)(gB + k0 + 32 + rowK64);
        }
        bf16x8 af[4], bf[4];
#pragma unroll
        for (int i = 0; i < 4; ++i)
            af[i] = *(const bf16x8*)&As[buf][(wm * 64 + i * 16 + frow) * 32 + fk];
#pragma unroll
        for (int j = 0; j < 4; ++j)
            bf[j] = *(const bf16x8*)&Bs[buf][(wn * 64 + j * 16 + frow) * 32 + fk];
#pragma unroll
        for (int i = 0; i < 4; ++i)
#pragma unroll
            for (int j = 0; j < 4; ++j)
                acc[i][j] = __builtin_amdgcn_mfma_f32_16x16x32_bf16(af[i], bf[j], acc[i][j], 0, 0, 0);
        if (!last) {
            const int nb = buf ^ 1;
            *(uint4*)&As[nb][ls] = ra0; *(uint4*)&As[nb][2048 + ls] = ra1;
            *(uint4*)&Bs[nb][ls] = rb0; *(uint4*)&Bs[nb][2048 + ls] = rb1;
            __syncthreads();
            buf = nb;
        }
    }

    // epilogue: C/D layout col=lane&15, row=(lane>>4)*4+reg  [m89/m91-verified]
    const int quad = lane >> 4;
#pragma unroll
    for (int i = 0; i < 4; ++i) {
        const int row = n0 + wm * 64 + i * 16 + quad * 4;
#pragma unroll
        for (int j = 0; j < 4; ++j) {
            const int col = m0 + wn * 64 + j * 16 + (lane & 15);
            const float bv = bias ? bias[col] : 0.f;
#pragma unroll
            for (int r = 0; r < 4; ++r) {
                float v = acc[i][j][r] + bv;
                if (ACT == 1) v = dswishf_(v);
                if (HAS_RES) v += res[(size_t)(row + r) * M + col];
                v = clampd_(v);
                if (O32) out32[(size_t)(row + r) * M + col] = v;
                if (O16) out16[(size_t)(row + r) * M + col] = f2bf_(v);
            }
        }
    }
}

// ---------------------------------------------------------------------------
// Same dbuf GEMM body with fused epilogues.
// EPI=0 (qkv): A=xb(8192x512), W=in_proj(1536x512), bias=ipb. Writes
//   qu/qv/k/v bf16 in [b*8+h][t][d] layout, q scaled 0.125 + u/v bias.
// EPI=1 (pos): A=pos_b(1024x512), W=linear_pos(512x512), no bias. Writes
//   p_b[h][j][d] bf16.
// ---------------------------------------------------------------------------
template <int EPI>
__global__ __launch_bounds__(256) void gemm_fused(
    const u16* __restrict__ A, const u16* __restrict__ W,
    const float* __restrict__ bias, const float* __restrict__ ub, const float* __restrict__ vb,
    u16* __restrict__ o_qu, u16* __restrict__ o_qv, u16* __restrict__ o_k,
    u16* __restrict__ o_v, u16* __restrict__ o_p, int N, int K, int M)
{
    __shared__ __align__(16) u16 As[2][128 * 32];
    __shared__ __align__(16) u16 Bs[2][128 * 32];
    const int tid  = threadIdx.x;
    const int wv   = tid >> 6;
    const int lane = tid & 63;
    const int wm   = wv >> 1, wn = wv & 1;
    const int m0 = blockIdx.x * 128;
    const int n0 = blockIdx.y * 128;

    const int sc_ = tid & 3;
    const int sr_ = tid >> 2;
    const u16* gA = A + (size_t)(n0 + sr_) * K + sc_ * 8;
    const u16* gB = W + (size_t)(m0 + sr_) * K + sc_ * 8;
    const int ls = sr_ * 32 + sc_ * 8;
    const size_t rowK64 = (size_t)64 * K;

    f32x4 acc[4][4];
#pragma unroll
    for (int i = 0; i < 4; ++i)
#pragma unroll
        for (int j = 0; j < 4; ++j) acc[i][j] = (f32x4)0.f;

    const int frow = (lane & 15);
    const int fk   = (lane >> 4) * 8;

    uint4 ra0 = *(const uint4*)(gA);
    uint4 ra1 = *(const uint4*)(gA + rowK64);
    uint4 rb0 = *(const uint4*)(gB);
    uint4 rb1 = *(const uint4*)(gB + rowK64);
    *(uint4*)&As[0][ls] = ra0; *(uint4*)&As[0][2048 + ls] = ra1;
    *(uint4*)&Bs[0][ls] = rb0; *(uint4*)&Bs[0][2048 + ls] = rb1;
    __syncthreads();

    int buf = 0;
    for (int k0 = 0; k0 < K; k0 += 32) {
        const bool last = (k0 + 32 >= K);
        if (!last) {
            ra0 = *(const uint4*)(gA + k0 + 32);
            ra1 = *(const uint4*)(gA + k0 + 32 + rowK64);
            rb0 = *(const uint4*)(gB + k0 + 32);
            rb1 = *(const uint4*)(gB + k0 + 32 + rowK64);
        }
        bf16x8 af[4], bf[4];
#pragma unroll
        for (int i = 0; i < 4; ++i)
            af[i] = *(const bf16x8*)&As[buf][(wm * 64 + i * 16 + frow) * 32 + fk];
#pragma unroll
        for (int j = 0; j < 4; ++j)
            bf[j] = *(const bf16x8*)&Bs[buf][(wn * 64 + j * 16 + frow) * 32 + fk];
#pragma unroll
        for (int i = 0; i < 4; ++i)
#pragma unroll
            for (int j = 0; j < 4; ++j)
                acc[i][j] = __builtin_amdgcn_mfma_f32_16x16x32_bf16(af[i], bf[j], acc[i][j], 0, 0, 0);
        if (!last) {
            const int nb = buf ^ 1;
            *(uint4*)&As[nb][ls] = ra0; *(uint4*)&As[nb][2048 + ls] = ra1;
            *(uint4*)&Bs[nb][ls] = rb0; *(uint4*)&Bs[nb][2048 + ls] = rb1;
            __syncthreads();
            buf = nb;
        }
    }

    const int quad = lane >> 4;
#pragma unroll
    for (int i = 0; i < 4; ++i) {
        const int rowb = n0 + wm * 64 + i * 16 + quad * 4;
#pragma unroll
        for (int j = 0; j < 4; ++j) {
            const int col = m0 + wn * 64 + j * 16 + (lane & 15);
            if (EPI == 0) {
                const float bv = bias[col];
                const int c = col & 511, h = c >> 6, d = c & 63;
#pragma unroll
                for (int r = 0; r < 4; ++r) {
                    const int row = rowb + r;
                    const float v = clampd_(acc[i][j][r] + bv);
                    const int t = row >> 4, b = row & 15;
                    const size_t dst = ((size_t)(b * 8 + h) * 512 + t) * 64 + d;
                    if (col < 512) {
                        o_qu[dst] = f2bf_(v * 0.125f + ub[c]);
                        o_qv[dst] = f2bf_(v * 0.125f + vb[c]);
                    } else if (col < 1024) {
                        o_k[dst] = f2bf_(v);
                    } else {
                        o_v[dst] = f2bf_(v);
                    }
                }
            } else {
                const int h = col >> 6, d = col & 63;
#pragma unroll
                for (int r = 0; r < 4; ++r)
                    o_p[(size_t)h * 65536 + (size_t)(rowb + r) * 64 + d] = f2bf_(acc[i][j][r]);
            }
        }
    }
}

// ---------------------------------------------------------------------------
// f32 -> bf16 converters
// ---------------------------------------------------------------------------
__device__ __forceinline__ void store_bf4_(u16* out, float4 v) {
    const unsigned lo = (unsigned)f2bf_(v.x) | ((unsigned)f2bf_(v.y) << 16);
    const unsigned hi = (unsigned)f2bf_(v.z) | ((unsigned)f2bf_(v.w) << 16);
    *(uint2*)out = make_uint2(lo, hi);
}

__global__ __launch_bounds__(256) void cvt_k(const float* __restrict__ in, u16* __restrict__ out)
{
    const int i4 = (blockIdx.x * 256 + threadIdx.x) * 4;
    store_bf4_(out + i4, *(const float4*)(in + i4));
}

struct WPtrs { const float* p[9]; };
__global__ __launch_bounds__(256) void cvt_w_k(WPtrs wp, u16* __restrict__ out)
{
    static const int off[10] = {0, 1048576, 2097152, 3145728, 4194304,
                                4980736, 5242880, 5505024, 6029312, 6291456};
    const int e = (blockIdx.x * 256 + threadIdx.x) * 4;
    int r = 0;
#pragma unroll
    for (int k = 1; k < 9; ++k) r += (e >= off[k]);
    store_bf4_(out + e, *(const float4*)(wp.p[r] + (e - off[r])));
}

// pos_emb (1023x512) -> bf16 padded to 1024 rows (row 1023 = 0)
__global__ __launch_bounds__(256) void cvt_pos_k(const float* __restrict__ in, u16* __restrict__ out)
{
    const int e = (blockIdx.x * 256 + threadIdx.x) * 4;
    float4 v = make_float4(0.f, 0.f, 0.f, 0.f);
    if (e < 1023 * 512) v = *(const float4*)(in + e);
    store_bf4_(out + e, v);
}

// ---------------------------------------------------------------------------
// C2[bhl][t][j] = qv[t,:] . p[h][j,:]  (K=64 MFMA gemm, bf16 out, 1024 cols)
// grid (j-tiles=8, t-tiles=4, bhl=32)   [R6-proven]
// ---------------------------------------------------------------------------
__global__ __launch_bounds__(256) void c2_mfma(
    const u16* __restrict__ qv_b, const u16* __restrict__ p_b,
    u16* __restrict__ c2b, int b0)
{
    __shared__ __align__(16) u16 As[128 * 32];
    __shared__ __align__(16) u16 Bs[128 * 32];
    const int tid  = threadIdx.x;
    const int wv   = tid >> 6;
    const int lane = tid & 63;
    const int wm   = wv >> 1, wn = wv & 1;
    const int m0 = blockIdx.x * 128;     // j
    const int n0 = blockIdx.y * 128;     // t
    const int bhl = blockIdx.z;
    const int gbh = b0 * 8 + bhl;
    const int h = bhl & 7;

    const int K = 64;
    const u16* A = qv_b + (size_t)gbh * 512 * 64;
    const u16* W = p_b + (size_t)h * 1024 * 64;

    const int sc_ = tid & 3;
    const int sr_ = tid >> 2;
    const u16* gA = A + (size_t)(n0 + sr_) * K + sc_ * 8;
    const u16* gB = W + (size_t)(m0 + sr_) * K + sc_ * 8;
    const int ls = sr_ * 32 + sc_ * 8;
    const size_t rowK64 = (size_t)64 * K;

    f32x4 acc[4][4];
#pragma unroll
    for (int i = 0; i < 4; ++i)
#pragma unroll
        for (int j = 0; j < 4; ++j) acc[i][j] = (f32x4)0.f;

    const int frow = (lane & 15);
    const int fk   = (lane >> 4) * 8;

    for (int k0 = 0; k0 < K; k0 += 32) {
        const uint4 a0 = *(const uint4*)(gA + k0);
        const uint4 a1 = *(const uint4*)(gA + k0 + rowK64);
        const uint4 b0v = *(const uint4*)(gB + k0);
        const uint4 b1v = *(const uint4*)(gB + k0 + rowK64);
        *(uint4*)&As[ls]        = a0;
        *(uint4*)&As[2048 + ls] = a1;
        *(uint4*)&Bs[ls]        = b0v;
        *(uint4*)&Bs[2048 + ls] = b1v;
        __syncthreads();
        bf16x8 af[4], bf[4];
#pragma unroll
        for (int i = 0; i < 4; ++i)
            af[i] = *(const bf16x8*)&As[(wm * 64 + i * 16 + frow) * 32 + fk];
#pragma unroll
        for (int j = 0; j < 4; ++j)
            bf[j] = *(const bf16x8*)&Bs[(wn * 64 + j * 16 + frow) * 32 + fk];
#pragma unroll
        for (int i = 0; i < 4; ++i)
#pragma unroll
            for (int j = 0; j < 4; ++j)
                acc[i][j] = __builtin_amdgcn_mfma_f32_16x16x32_bf16(af[i], bf[j], acc[i][j], 0, 0, 0);
        __syncthreads();
    }

    const int quad = lane >> 4;
    u16* outb = c2b + (size_t)bhl * 512 * 1024;
#pragma unroll
    for (int i = 0; i < 4; ++i) {
        const int row = n0 + wm * 64 + i * 16 + quad * 4;
#pragma unroll
        for (int j = 0; j < 4; ++j) {
            const int col = m0 + wn * 64 + j * 16 + (lane & 15);
#pragma unroll
            for (int r = 0; r < 4; ++r)
                outb[(size_t)(row + r) * 1024 + col] = f2bf_(acc[i][j][r]);
        }
    }
}

// ---------------------------------------------------------------------------
// scores[bhl][t][s] = qu[t,:].k[s,:] + C2[bhl][t][511-t+s]   (f32 out, clamped)
// grid (s-tiles=4, t-tiles=4, bhl=32)   [R6-proven]
// ---------------------------------------------------------------------------
__global__ __launch_bounds__(256) void scores_c1(
    const u16* __restrict__ qu_b, const u16* __restrict__ k_b,
    const u16* __restrict__ c2b, float* __restrict__ sc, int b0)
{
    __shared__ __align__(16) u16 As[128 * 32];
    __shared__ __align__(16) u16 Bs[128 * 32];
    const int tid  = threadIdx.x;
    const int wv   = tid >> 6;
    const int lane = tid & 63;
    const int wm   = wv >> 1, wn = wv & 1;
    const int m0 = blockIdx.x * 128;     // s
    const int n0 = blockIdx.y * 128;     // t
    const int bhl = blockIdx.z;
    const int gbh = b0 * 8 + bhl;

    const int K = 64;
    const u16* A = qu_b + (size_t)gbh * 512 * 64;
    const u16* W = k_b + (size_t)gbh * 512 * 64;

    const int sc_ = tid & 3;
    const int sr_ = tid >> 2;
    const u16* gA = A + (size_t)(n0 + sr_) * K + sc_ * 8;
    const u16* gB = W + (size_t)(m0 + sr_) * K + sc_ * 8;
    const int ls = sr_ * 32 + sc_ * 8;
    const size_t rowK64 = (size_t)64 * K;

    f32x4 acc[4][4];
#pragma unroll
    for (int i = 0; i < 4; ++i)
#pragma unroll
        for (int j = 0; j < 4; ++j) acc[i][j] = (f32x4)0.f;

    const int frow = (lane & 15);
    const int fk   = (lane >> 4) * 8;

    for (int k0 = 0; k0 < K; k0 += 32) {
        const uint4 a0 = *(const uint4*)(gA + k0);
        const uint4 a1 = *(const uint4*)(gA + k0 + rowK64);
        const uint4 b0v = *(const uint4*)(gB + k0);
        const uint4 b1v = *(const uint4*)(gB + k0 + rowK64);
        *(uint4*)&As[ls]        = a0;
        *(uint4*)&As[2048 + ls] = a1;
        *(uint4*)&Bs[ls]        = b0v;
        *(uint4*)&Bs[2048 + ls] = b1v;
        __syncthreads();
        bf16x8 af[4], bf[4];
#pragma unroll
        for (int i = 0; i < 4; ++i)
            af[i] = *(const bf16x8*)&As[(wm * 64 + i * 16 + frow) * 32 + fk];
#pragma unroll
        for (int j = 0; j < 4; ++j)
            bf[j] = *(const bf16x8*)&Bs[(wn * 64 + j * 16 + frow) * 32 + fk];
#pragma unroll
        for (int i = 0; i < 4; ++i)
#pragma unroll
            for (int j = 0; j < 4; ++j)
                acc[i][j] = __builtin_amdgcn_mfma_f32_16x16x32_bf16(af[i], bf[j], acc[i][j], 0, 0, 0);
        __syncthreads();
    }

    const int quad = lane >> 4;
    const u16* c2base = c2b + (size_t)bhl * 512 * 1024;
    float* scb = sc + (size_t)bhl * 512 * 512;
#pragma unroll
    for (int i = 0; i < 4; ++i) {
        const int row = n0 + wm * 64 + i * 16 + quad * 4;
#pragma unroll
        for (int j = 0; j < 4; ++j) {
            const int col = m0 + wn * 64 + j * 16 + (lane & 15);
#pragma unroll
            for (int r = 0; r < 4; ++r) {
                const int t = row + r;
                const float bd = bf2f_(c2base[(size_t)t * 1024 + (511 - t + col)]);
                scb[(size_t)t * 512 + col] = clampd_(acc[i][j][r] + bd);
            }
        }
    }
}

// softmax over 512-long rows: f32 scores in -> bf16 probs out
__global__ __launch_bounds__(256) void softmax_rows(
    const float* __restrict__ s, u16* __restrict__ p)
{
    const int row = blockIdx.x * 4 + (threadIdx.x >> 6);
    const int lane = threadIdx.x & 63;
    const float* r = s + (size_t)row * 512;
    u16* o = p + (size_t)row * 512;
    float v[8];
    float mx = -1e30f;
#pragma unroll
    for (int j = 0; j < 8; ++j) { v[j] = r[lane + (j << 6)]; mx = fmaxf(mx, v[j]); }
#pragma unroll
    for (int off = 32; off > 0; off >>= 1) mx = fmaxf(mx, __shfl_xor(mx, off, 64));
    float sum = 0.f;
#pragma unroll
    for (int j = 0; j < 8; ++j) { v[j] = __expf(v[j] - mx); sum += v[j]; }
#pragma unroll
    for (int off = 32; off > 0; off >>= 1) sum += __shfl_xor(sum, off, 64);
    const float inv = 1.f / sum;
#pragma unroll
    for (int j = 0; j < 8; ++j) o[lane + (j << 6)] = f2bf_(v[j] * inv);
}

// ---------------------------------------------------------------------------
// PV: ao[(t*16+b)*512 + h*64+d] = sum_s probs[bhl][t][s] * v[gbh][s][d]
// grid (t-tiles=4, bhl=32)   [R6-proven]
// ---------------------------------------------------------------------------
__global__ __launch_bounds__(256) void pv_mfma(
    const u16* __restrict__ probs, const u16* __restrict__ v_b,
    u16* __restrict__ aob, int b0)
{
    __shared__ __align__(16) u16 Ps[128 * 32];
    __shared__ __align__(16) u16 Vt[64 * 32];
    const int tid  = threadIdx.x;
    const int wv   = tid >> 6;
    const int lane = tid & 63;
    const int t0 = blockIdx.x * 128;
    const int bhl = blockIdx.y;
    const int gbh = b0 * 8 + bhl;
    const int b = gbh >> 3, h = gbh & 7;

    const u16* prow = probs + (size_t)bhl * 512 * 512;
    const u16* vrow = v_b + (size_t)gbh * 512 * 64;

    f32x4 acc[2][4];
#pragma unroll
    for (int i = 0; i < 2; ++i)
#pragma unroll
        for (int j = 0; j < 4; ++j) acc[i][j] = (f32x4)0.f;

    const int frow = (lane & 15);
    const int fk   = (lane >> 4) * 8;
    const int pl0 = tid * 2;
    const int vss = tid >> 3, vdd = tid & 7;

    for (int s0 = 0; s0 < 512; s0 += 32) {
#pragma unroll
        for (int q = 0; q < 2; ++q) {
            const int lin = pl0 + q;
            const int tt = lin >> 2, ch = lin & 3;
            *(uint4*)&Ps[tt * 32 + ch * 8] =
                *(const uint4*)(prow + (size_t)(t0 + tt) * 512 + s0 + ch * 8);
        }
        uint4 vv = *(const uint4*)(vrow + (size_t)(s0 + vss) * 64 + vdd * 8);
        const u16* vu = (const u16*)&vv;
#pragma unroll
        for (int q = 0; q < 8; ++q)
            Vt[(vdd * 8 + q) * 32 + vss] = vu[q];
        __syncthreads();
        bf16x8 af[2], bf[4];
#pragma unroll
        for (int i = 0; i < 2; ++i)
            af[i] = *(const bf16x8*)&Ps[(wv * 32 + i * 16 + frow) * 32 + fk];
#pragma unroll
        for (int j = 0; j < 4; ++j)
            bf[j] = *(const bf16x8*)&Vt[(j * 16 + frow) * 32 + fk];
#pragma unroll
        for (int i = 0; i < 2; ++i)
#pragma unroll
            for (int j = 0; j < 4; ++j)
                acc[i][j] = __builtin_amdgcn_mfma_f32_16x16x32_bf16(af[i], bf[j], acc[i][j], 0, 0, 0);
        __syncthreads();
    }

    const int quad = lane >> 4;
#pragma unroll
    for (int i = 0; i < 2; ++i) {
        const int trow = t0 + wv * 32 + i * 16 + quad * 4;
#pragma unroll
        for (int j = 0; j < 4; ++j) {
            const int d = j * 16 + (lane & 15);
#pragma unroll
            for (int r = 0; r < 4; ++r)
                aob[((size_t)(trow + r) * B_SZ + b) * 512 + h * 64 + d] = f2bf_(acc[i][j][r]);
        }
    }
}

// ---------------------------------------------------------------------------
// Conv-module pieces (bf16 chain)
// ---------------------------------------------------------------------------
// GLU over (n,1024) bf16 rows -> (n,512) bf16; 4 channels per thread.
__global__ __launch_bounds__(256) void glu_k(const u16* __restrict__ in, u16* __restrict__ out)
{
    const int i4 = (blockIdx.x * 256 + threadIdx.x) * 4;
    const int n = i4 >> 9, c = i4 & 511;
    const uint2 av = *(const uint2*)(in + (size_t)n * 1024 + c);
    const uint2 gv = *(const uint2*)(in + (size_t)n * 1024 + 512 + c);
    const u16* au = (const u16*)&av;
    const u16* gu = (const u16*)&gv;
    u16 o[4];
#pragma unroll
    for (int q = 0; q < 4; ++q) {
        const float a = bf2f_(au[q]), g = bf2f_(gu[q]);
        o[q] = f2bf_(a * sigmoidf_(g));
    }
    *(uint2*)(out + i4) = *(uint2*)o;
}

// dw weight transpose: w[c][j] (512x31) -> wT[j][c] (31x512)
__global__ __launch_bounds__(256) void dwt_k(const float* __restrict__ w, float* __restrict__ wT)
{
    const int idx = blockIdx.x * 256 + threadIdx.x;
    if (idx >= 31 * 512) return;
    const int j = idx >> 9, c = idx & 511;
    wT[idx] = w[c * 31 + j];
}

// causal depthwise conv (K=31, pad 30) + DoubleSwish; bf16 in -> bf16 out.
// 8 t-outputs per thread, sliding register window, coalesced wT loads.
__global__ __launch_bounds__(256) void dwconv_k(
    const u16* __restrict__ g, const float* __restrict__ wT,
    const float* __restrict__ bb, u16* __restrict__ out)
{
    const int idx = blockIdx.x * 256 + threadIdx.x;   // [0, 64*16*512)
    const int c = idx & 511;
    const int b = (idx >> 9) & 15;
    const int t0 = (idx >> 13) * 8;
    float wr[31];
#pragma unroll
    for (int j = 0; j < 31; ++j) wr[j] = wT[j * 512 + c];
    float win[38];
#pragma unroll
    for (int jj = 0; jj < 38; ++jj) {
        const int tt = t0 - 30 + jj;
        win[jj] = (tt >= 0) ? bf2f_(g[((size_t)tt * B_SZ + b) * 512 + c]) : 0.f;
    }
    const float bias = bb[c];
#pragma unroll
    for (int o = 0; o < 8; ++o) {
        float acc = bias;
#pragma unroll
        for (int j = 0; j < 31; ++j) acc += win[o + j] * wr[j];
        out[((size_t)(t0 + o) * B_SZ + b) * 512 + c] = f2bf_(dswishf_(acc));
    }
}

__global__ __launch_bounds__(256) void norm_k(float* __restrict__ x)
{
    const int row = blockIdx.x * 4 + (threadIdx.x >> 6);
    const int lane = threadIdx.x & 63;
    float* r = x + (size_t)row * 512;
    float v[8];
    float ss = 0.f;
#pragma unroll
    for (int j = 0; j < 8; ++j) { v[j] = r[lane + (j << 6)]; ss += v[j] * v[j]; }
#pragma unroll
    for (int o = 32; o > 0; o >>= 1) ss += __shfl_xor(ss, o, 64);
    const float scale = rsqrtf(ss * (1.f / 512.f) + EPS_BN);
#pragma unroll
    for (int j = 0; j < 8; ++j) r[lane + (j << 6)] = v[j] * scale;
}

// ---------------------------------------------------------------------------
extern "C" void kernel_launch(void* const* d_in, const int* in_sizes, int n_in,
                              void* d_out, int out_size, void* d_ws, size_t ws_size,
                              hipStream_t stream)
{
    const float* src   = (const float*)d_in[0];
    const float* pos   = (const float*)d_in[1];
    const float* fm_w1 = (const float*)d_in[2];
    const float* fm_b1 = (const float*)d_in[3];
    const float* fm_w2 = (const float*)d_in[4];
    const float* fm_b2 = (const float*)d_in[5];
    const float* f_w1  = (const float*)d_in[6];
    const float* f_b1  = (const float*)d_in[7];
    const float* f_w2  = (const float*)d_in[8];
    const float* f_b2  = (const float*)d_in[9];
    const float* ipw   = (const float*)d_in[10];
    const float* ipb   = (const float*)d_in[11];
    const float* opw   = (const float*)d_in[12];
    const float* opb   = (const float*)d_in[13];
    const float* lpw   = (const float*)d_in[14];
    const float* pbu   = (const float*)d_in[15];
    const float* pbv   = (const float*)d_in[16];
    const float* cpw1  = (const float*)d_in[17];
    const float* cpb1  = (const float*)d_in[18];
    const float* cdw   = (const float*)d_in[19];
    const float* cdb   = (const float*)d_in[20];
    const float* cpw2  = (const float*)d_in[21];
    const float* cpb2  = (const float*)d_in[22];

    float* x = (float*)d_out;              // running activation (8192 x 512) f32

    // ---- workspace layout (~157.3 MB) ----
    char* base = (char*)d_ws;
    u16*   wb    = (u16*)base;   base += 6291456ull * 2;   // 9 weights bf16
    u16*   src_b = (u16*)base;   base += 4194304ull * 2;
    u16*   pos_b = (u16*)base;   base += 524288ull * 2;    // 1024x512 padded
    u16*   xb    = (u16*)base;   base += 4194304ull * 2;
    u16*   hb    = (u16*)base;   base += 16777216ull * 2;  // FFN hidden / c2b / dwconv out
    u16*   aob   = (u16*)base;   base += 4194304ull * 2;
    u16*   qu_b  = (u16*)base;   base += 4194304ull * 2;
    u16*   qv_b  = (u16*)base;   base += 4194304ull * 2;
    u16*   k_b   = (u16*)base;   base += 4194304ull * 2;
    u16*   v_b   = (u16*)base;   base += 4194304ull * 2;
    u16*   p_b   = (u16*)base;   base += 524288ull * 2;    // [8][1024][64]
    float* wTd   = (float*)base; base += 15872ull * 4;
    float* scr   = (float*)base; base += 12582912ull * 4;  // 50.3 MB shared scratch

    float* sc    = scr;                        // 32x512x512 f32 (attention)
    u16*   probs = (u16*)(scr + 8388608);      // 32x512x512 bf16 (attention)
    u16*   pw1_o = (u16*)scr;                  // 8192x1024 bf16 (conv)
    u16*   glu_o = ((u16*)scr) + 8388608;      // 8192x512 bf16 (conv)
    u16*   c2b   = hb;                         // 32x512x1024 bf16 (attention)

    u16* fm_w1b = wb;
    u16* fm_w2b = wb + 1048576;
    u16* f_w1b  = wb + 2097152;
    u16* f_w2b  = wb + 3145728;
    u16* ipwb   = wb + 4194304;
    u16* opwb   = wb + 4980736;
    u16* lpwb   = wb + 5242880;
    u16* cpw1b  = wb + 5505024;
    u16* cpw2b  = wb + 6029312;

    const dim3 blk(256);

    // 0) f32 -> bf16 conversions
    WPtrs wp = {{fm_w1, fm_w2, f_w1, f_w2, ipw, opw, lpw, cpw1, cpw2}};
    cvt_w_k<<<dim3(6291456 / 1024), blk, 0, stream>>>(wp, wb);
    cvt_k<<<dim3(4194304 / 1024), blk, 0, stream>>>(src, src_b);
    cvt_pos_k<<<dim3(524288 / 1024), blk, 0, stream>>>(pos, pos_b);
    dwt_k<<<dim3(62), blk, 0, stream>>>(cdw, wTd);

    // 1) macaron FFN: x = src + W2 @ dswish(W1 @ src)
    gemm_mfma<1, false, false, true><<<dim3(16, 64), blk, 0, stream>>>(
        src_b, fm_w1b, fm_b1, nullptr, nullptr, hb, NROWS, 512, DFF_);
    gemm_mfma<0, true, true, true><<<dim3(4, 64), blk, 0, stream>>>(
        hb, fm_w2b, fm_b2, src, x, xb, NROWS, DFF_, 512);

    // 2) qkv / pos projections with fused repack epilogues
    gemm_fused<0><<<dim3(12, 64), blk, 0, stream>>>(
        xb, ipwb, ipb, pbu, pbv, qu_b, qv_b, k_b, v_b, nullptr, NROWS, 512, 1536);
    gemm_fused<1><<<dim3(4, 8), blk, 0, stream>>>(
        pos_b, lpwb, nullptr, nullptr, nullptr,
        nullptr, nullptr, nullptr, nullptr, p_b, 1024, 512, 512);

    // 3) MFMA rel-pos attention, chunked over batch (32 bh per chunk)
    for (int bc = 0; bc < B_SZ / BCHUNK; ++bc) {
        const int b0 = bc * BCHUNK;
        c2_mfma<<<dim3(8, 4, 32), blk, 0, stream>>>(qv_b, p_b, c2b, b0);
        scores_c1<<<dim3(4, 4, 32), blk, 0, stream>>>(qu_b, k_b, c2b, sc, b0);
        softmax_rows<<<dim3(32 * 512 / 4), blk, 0, stream>>>(sc, probs);
        pv_mfma<<<dim3(4, 32), blk, 0, stream>>>(probs, v_b, aob, b0);
    }

    // 4) out projection (residual into x)
    gemm_mfma<0, true, true, true><<<dim3(4, 64), blk, 0, stream>>>(
        aob, opwb, opb, x, x, xb, NROWS, 512, 512);

    // 5) conv module: pw1(bf16 out) -> GLU(bf16) -> dwconv(+dswish) -> pw2 (residual)
    gemm_mfma<0, false, false, true><<<dim3(8, 64), blk, 0, stream>>>(
        xb, cpw1b, cpb1, nullptr, nullptr, pw1_o, NROWS, 512, 1024);
    glu_k<<<dim3(NROWS * 512 / 1024), blk, 0, stream>>>(pw1_o, glu_o);
    dwconv_k<<<dim3(2048), blk, 0, stream>>>(glu_o, wTd, cdb, hb);
    gemm_mfma<0, true, true, true><<<dim3(4, 64), blk, 0, stream>>>(
        hb, cpw2b, cpb2, x, x, xb, NROWS, 512, 512);

    // 6) second FFN
    gemm_mfma<1, false, false, true><<<dim3(16, 64), blk, 0, stream>>>(
        xb, f_w1b, f_b1, nullptr, nullptr, hb, NROWS, 512, DFF_);
    gemm_mfma<0, true, true, false><<<dim3(4, 64), blk, 0, stream>>>(
        hb, f_w2b, f_b2, x, x, nullptr, NROWS, DFF_, 512);

    // 7) BasicNorm
    norm_k<<<dim3(NROWS / 4), blk, 0, stream>>>(x);
}

// Round 8
// 590.545 us; speedup vs baseline: 1.1340x; 1.1340x over previous
//
#include <hip/hip_runtime.h>
#include <math.h>

// Problem constants (ConformerEncoderLayer, T=512 B=16 C=512 H=8 d=64 DFF=2048 K=31)
#define T_SEQ 512
#define B_SZ  16
#define C_DIM 512
#define NH    8
#define HD    64
#define DFF_  2048
#define NROWS (T_SEQ * B_SZ)   // 8192 rows of (t*B+b)
#define EPS_BN 1.2840254166877414f  // exp(0.25)

typedef unsigned short u16;
typedef __attribute__((ext_vector_type(8))) short bf16x8;
typedef __attribute__((ext_vector_type(4))) float f32x4;

__device__ __forceinline__ float sigmoidf_(float x) { return 1.f / (1.f + __expf(-x)); }
__device__ __forceinline__ float dswishf_(float x)  { return x * sigmoidf_(x - 1.f); }
__device__ __forceinline__ float clampd_(float x)   { return fminf(fmaxf(x, -1e4f), 1e4f); }
__device__ __forceinline__ u16 f2bf_(float x) {
    unsigned u = __float_as_uint(x);
    return (u16)((u + 0x7fffu + ((u >> 16) & 1u)) >> 16);
}
__device__ __forceinline__ float bf2f_(u16 u) {
    return __uint_as_float(((unsigned)u) << 16);
}

// ---------------------------------------------------------------------------
// bf16 MFMA GEMM, double-buffered LDS (R7-proven): out = [res +] act(A@W^T + b)
// 128x128 tile, BK=32, 4 waves (2x2 of 64x64). N,M mult of 128; K mult of 32.
// ---------------------------------------------------------------------------
template <int ACT, bool HAS_RES, bool O32, bool O16>
__global__ __launch_bounds__(256) void gemm_mfma(
    const u16* __restrict__ A, const u16* __restrict__ W,
    const float* __restrict__ bias, const float* __restrict__ res,
    float* __restrict__ out32, u16* __restrict__ out16, int N, int K, int M)
{
    __shared__ __align__(16) u16 As[2][128 * 32];
    __shared__ __align__(16) u16 Bs[2][128 * 32];
    const int tid  = threadIdx.x;
    const int wv   = tid >> 6;
    const int lane = tid & 63;
    const int wm   = wv >> 1, wn = wv & 1;
    const int m0 = blockIdx.x * 128;
    const int n0 = blockIdx.y * 128;

    const int sc_ = tid & 3;
    const int sr_ = tid >> 2;
    const u16* gA = A + (size_t)(n0 + sr_) * K + sc_ * 8;
    const u16* gB = W + (size_t)(m0 + sr_) * K + sc_ * 8;
    const int ls = sr_ * 32 + sc_ * 8;
    const size_t rowK64 = (size_t)64 * K;

    f32x4 acc[4][4];
#pragma unroll
    for (int i = 0; i < 4; ++i)
#pragma unroll
        for (int j = 0; j < 4; ++j) acc[i][j] = (f32x4)0.f;

    const int frow = (lane & 15);
    const int fk   = (lane >> 4) * 8;

    uint4 ra0 = *(const uint4*)(gA);
    uint4 ra1 = *(const uint4*)(gA + rowK64);
    uint4 rb0 = *(const uint4*)(gB);
    uint4 rb1 = *(const uint4*)(gB + rowK64);
    *(uint4*)&As[0][ls] = ra0; *(uint4*)&As[0][2048 + ls] = ra1;
    *(uint4*)&Bs[0][ls] = rb0; *(uint4*)&Bs[0][2048 + ls] = rb1;
    __syncthreads();

    int buf = 0;
    for (int k0 = 0; k0 < K; k0 += 32) {
        const bool last = (k0 + 32 >= K);
        if (!last) {
            ra0 = *(const uint4*)(gA + k0 + 32);
            ra1 = *(const uint4*)(gA + k0 + 32 + rowK64);
            rb0 = *(const uint4*)(gB + k0 + 32);
            rb1 = *(const uint4*)(gB + k0 + 32 + rowK64);
        }
        bf16x8 af[4], bf[4];
#pragma unroll
        for (int i = 0; i < 4; ++i)
            af[i] = *(const bf16x8*)&As[buf][(wm * 64 + i * 16 + frow) * 32 + fk];
#pragma unroll
        for (int j = 0; j < 4; ++j)
            bf[j] = *(const bf16x8*)&Bs[buf][(wn * 64 + j * 16 + frow) * 32 + fk];
#pragma unroll
        for (int i = 0; i < 4; ++i)
#pragma unroll
            for (int j = 0; j < 4; ++j)
                acc[i][j] = __builtin_amdgcn_mfma_f32_16x16x32_bf16(af[i], bf[j], acc[i][j], 0, 0, 0);
        if (!last) {
            const int nb = buf ^ 1;
            *(uint4*)&As[nb][ls] = ra0; *(uint4*)&As[nb][2048 + ls] = ra1;
            *(uint4*)&Bs[nb][ls] = rb0; *(uint4*)&Bs[nb][2048 + ls] = rb1;
            __syncthreads();
            buf = nb;
        }
    }

    const int quad = lane >> 4;
#pragma unroll
    for (int i = 0; i < 4; ++i) {
        const int row = n0 + wm * 64 + i * 16 + quad * 4;
#pragma unroll
        for (int j = 0; j < 4; ++j) {
            const int col = m0 + wn * 64 + j * 16 + (lane & 15);
            const float bv = bias ? bias[col] : 0.f;
#pragma unroll
            for (int r = 0; r < 4; ++r) {
                float v = acc[i][j][r] + bv;
                if (ACT == 1) v = dswishf_(v);
                if (HAS_RES) v += res[(size_t)(row + r) * M + col];
                v = clampd_(v);
                if (O32) out32[(size_t)(row + r) * M + col] = v;
                if (O16) out16[(size_t)(row + r) * M + col] = f2bf_(v);
            }
        }
    }
}

// ---------------------------------------------------------------------------
// dbuf GEMM with fused epilogues (R7-proven).
// EPI=0 (qkv): writes qu/qv/k/v bf16 in [b*8+h][t][d], q*0.125 + u/v bias.
// EPI=1 (pos): writes p_b[h][j][d] bf16.
// ---------------------------------------------------------------------------
template <int EPI>
__global__ __launch_bounds__(256) void gemm_fused(
    const u16* __restrict__ A, const u16* __restrict__ W,
    const float* __restrict__ bias, const float* __restrict__ ub, const float* __restrict__ vb,
    u16* __restrict__ o_qu, u16* __restrict__ o_qv, u16* __restrict__ o_k,
    u16* __restrict__ o_v, u16* __restrict__ o_p, int N, int K, int M)
{
    __shared__ __align__(16) u16 As[2][128 * 32];
    __shared__ __align__(16) u16 Bs[2][128 * 32];
    const int tid  = threadIdx.x;
    const int wv   = tid >> 6;
    const int lane = tid & 63;
    const int wm   = wv >> 1, wn = wv & 1;
    const int m0 = blockIdx.x * 128;
    const int n0 = blockIdx.y * 128;

    const int sc_ = tid & 3;
    const int sr_ = tid >> 2;
    const u16* gA = A + (size_t)(n0 + sr_) * K + sc_ * 8;
    const u16* gB = W + (size_t)(m0 + sr_) * K + sc_ * 8;
    const int ls = sr_ * 32 + sc_ * 8;
    const size_t rowK64 = (size_t)64 * K;

    f32x4 acc[4][4];
#pragma unroll
    for (int i = 0; i < 4; ++i)
#pragma unroll
        for (int j = 0; j < 4; ++j) acc[i][j] = (f32x4)0.f;

    const int frow = (lane & 15);
    const int fk   = (lane >> 4) * 8;

    uint4 ra0 = *(const uint4*)(gA);
    uint4 ra1 = *(const uint4*)(gA + rowK64);
    uint4 rb0 = *(const uint4*)(gB);
    uint4 rb1 = *(const uint4*)(gB + rowK64);
    *(uint4*)&As[0][ls] = ra0; *(uint4*)&As[0][2048 + ls] = ra1;
    *(uint4*)&Bs[0][ls] = rb0; *(uint4*)&Bs[0][2048 + ls] = rb1;
    __syncthreads();

    int buf = 0;
    for (int k0 = 0; k0 < K; k0 += 32) {
        const bool last = (k0 + 32 >= K);
        if (!last) {
            ra0 = *(const uint4*)(gA + k0 + 32);
            ra1 = *(const uint4*)(gA + k0 + 32 + rowK64);
            rb0 = *(const uint4*)(gB + k0 + 32);
            rb1 = *(const uint4*)(gB + k0 + 32 + rowK64);
        }
        bf16x8 af[4], bf[4];
#pragma unroll
        for (int i = 0; i < 4; ++i)
            af[i] = *(const bf16x8*)&As[buf][(wm * 64 + i * 16 + frow) * 32 + fk];
#pragma unroll
        for (int j = 0; j < 4; ++j)
            bf[j] = *(const bf16x8*)&Bs[buf][(wn * 64 + j * 16 + frow) * 32 + fk];
#pragma unroll
        for (int i = 0; i < 4; ++i)
#pragma unroll
            for (int j = 0; j < 4; ++j)
                acc[i][j] = __builtin_amdgcn_mfma_f32_16x16x32_bf16(af[i], bf[j], acc[i][j], 0, 0, 0);
        if (!last) {
            const int nb = buf ^ 1;
            *(uint4*)&As[nb][ls] = ra0; *(uint4*)&As[nb][2048 + ls] = ra1;
            *(uint4*)&Bs[nb][ls] = rb0; *(uint4*)&Bs[nb][2048 + ls] = rb1;
            __syncthreads();
            buf = nb;
        }
    }

    const int quad = lane >> 4;
#pragma unroll
    for (int i = 0; i < 4; ++i) {
        const int rowb = n0 + wm * 64 + i * 16 + quad * 4;
#pragma unroll
        for (int j = 0; j < 4; ++j) {
            const int col = m0 + wn * 64 + j * 16 + (lane & 15);
            if (EPI == 0) {
                const float bv = bias[col];
                const int c = col & 511, h = c >> 6, d = c & 63;
#pragma unroll
                for (int r = 0; r < 4; ++r) {
                    const int row = rowb + r;
                    const float v = clampd_(acc[i][j][r] + bv);
                    const int t = row >> 4, b = row & 15;
                    const size_t dst = ((size_t)(b * 8 + h) * 512 + t) * 64 + d;
                    if (col < 512) {
                        o_qu[dst] = f2bf_(v * 0.125f + ub[c]);
                        o_qv[dst] = f2bf_(v * 0.125f + vb[c]);
                    } else if (col < 1024) {
                        o_k[dst] = f2bf_(v);
                    } else {
                        o_v[dst] = f2bf_(v);
                    }
                }
            } else {
                const int h = col >> 6, d = col & 63;
#pragma unroll
                for (int r = 0; r < 4; ++r)
                    o_p[(size_t)h * 65536 + (size_t)(rowb + r) * 64 + d] = f2bf_(acc[i][j][r]);
            }
        }
    }
}

// ---------------------------------------------------------------------------
// f32 -> bf16 converters
// ---------------------------------------------------------------------------
__device__ __forceinline__ void store_bf4_(u16* out, float4 v) {
    const unsigned lo = (unsigned)f2bf_(v.x) | ((unsigned)f2bf_(v.y) << 16);
    const unsigned hi = (unsigned)f2bf_(v.z) | ((unsigned)f2bf_(v.w) << 16);
    *(uint2*)out = make_uint2(lo, hi);
}

__global__ __launch_bounds__(256) void cvt_k(const float* __restrict__ in, u16* __restrict__ out)
{
    const int i4 = (blockIdx.x * 256 + threadIdx.x) * 4;
    store_bf4_(out + i4, *(const float4*)(in + i4));
}

struct WPtrs { const float* p[9]; };
__global__ __launch_bounds__(256) void cvt_w_k(WPtrs wp, u16* __restrict__ out)
{
    static const int off[10] = {0, 1048576, 2097152, 3145728, 4194304,
                                4980736, 5242880, 5505024, 6029312, 6291456};
    const int e = (blockIdx.x * 256 + threadIdx.x) * 4;
    int r = 0;
#pragma unroll
    for (int k = 1; k < 9; ++k) r += (e >= off[k]);
    store_bf4_(out + e, *(const float4*)(wp.p[r] + (e - off[r])));
}

// pos_emb (1023x512) -> bf16 padded to 1024 rows (row 1023 = 0)
__global__ __launch_bounds__(256) void cvt_pos_k(const float* __restrict__ in, u16* __restrict__ out)
{
    const int e = (blockIdx.x * 256 + threadIdx.x) * 4;
    float4 v = make_float4(0.f, 0.f, 0.f, 0.f);
    if (e < 1023 * 512) v = *(const float4*)(in + e);
    store_bf4_(out + e, v);
}

// v_b[gbh][s][d] -> vt_b[gbh][d][s]  (64x64 LDS tile transpose)
__global__ __launch_bounds__(256) void vt_k(const u16* __restrict__ in, u16* __restrict__ out)
{
    __shared__ u16 tile[64][65];
    const int s0 = blockIdx.x * 64;
    const int gbh = blockIdx.y;
    const u16* src = in + (size_t)gbh * 512 * 64;
    u16* dst = out + (size_t)gbh * 64 * 512;
    const int tid = threadIdx.x;
#pragma unroll
    for (int q = 0; q < 2; ++q) {
        const int lin = tid * 2 + q;             // 0..511 uint4s
        const int srow = lin >> 3, c8 = (lin & 7) * 8;
        const uint4 v = *(const uint4*)(src + (size_t)(s0 + srow) * 64 + c8);
        const u16* vu = (const u16*)&v;
#pragma unroll
        for (int e = 0; e < 8; ++e) tile[srow][c8 + e] = vu[e];
    }
    __syncthreads();
#pragma unroll
    for (int q = 0; q < 2; ++q) {
        const int lin = tid * 2 + q;
        const int d = lin >> 3, sc8 = (lin & 7) * 8;
        u16 o[8];
#pragma unroll
        for (int e = 0; e < 8; ++e) o[e] = tile[sc8 + e][d];
        *(uint4*)(dst + (size_t)d * 512 + s0 + sc8) = *(uint4*)o;
    }
}

// ---------------------------------------------------------------------------
// Fused flash rel-pos attention. grid (t64-tiles=8, gbh=128), 4 waves/block,
// each wave owns 16 t-rows. bd term computed on the fly as a 16x80 C2 window
// MFMA vs p_b (jlo = 496 - t0 + s0; col = 15 - tloc + sloc, always in [0,78];
// window rows <= 1023 within zero-padded p_b). K/V/P B-fragments read directly
// from global ([s][d] / [d][s] match B-operand layout). Online softmax per
// 16-lane quad via shfl. O accum f32, epilogue /l, writes ao (t,b,c) bf16.
// ---------------------------------------------------------------------------
__global__ __launch_bounds__(256) void flash_attn(
    const u16* __restrict__ qu_b, const u16* __restrict__ qv_b,
    const u16* __restrict__ k_b, const u16* __restrict__ vt_b,
    const u16* __restrict__ p_b, u16* __restrict__ aob)
{
    __shared__ __align__(16) u16 C2ld[4][16 * 80];
    __shared__ __align__(16) u16 Pld[4][16 * 64];
    const int tid = threadIdx.x;
    const int wv = tid >> 6;
    const int lane = tid & 63;
    const int quad = lane >> 4, ln = lane & 15;
    const int gbh = blockIdx.y;
    const int b = gbh >> 3, h = gbh & 7;
    const int t0 = blockIdx.x * 64 + wv * 16;     // wave's first t-row

    const u16* qu = qu_b + (size_t)gbh * 512 * 64;
    const u16* qv = qv_b + (size_t)gbh * 512 * 64;
    const u16* kb = k_b + (size_t)gbh * 512 * 64;
    const u16* vt = vt_b + (size_t)gbh * 64 * 512;
    const u16* pp = p_b + (size_t)h * 1024 * 64;

    // A-fragments (row = t0+ln, k = ks*32 + quad*8), constant across s-tiles
    bf16x8 aqu[2], aqv[2];
#pragma unroll
    for (int ks = 0; ks < 2; ++ks) {
        aqu[ks] = *(const bf16x8*)(qu + (size_t)(t0 + ln) * 64 + ks * 32 + quad * 8);
        aqv[ks] = *(const bf16x8*)(qv + (size_t)(t0 + ln) * 64 + ks * 32 + quad * 8);
    }

    f32x4 O[4];
#pragma unroll
    for (int nb = 0; nb < 4; ++nb) O[nb] = (f32x4)0.f;
    float m[4], l[4];
#pragma unroll
    for (int r = 0; r < 4; ++r) { m[r] = -1e30f; l[r] = 0.f; }

    u16* c2w = &C2ld[wv][0];
    u16* pw  = &Pld[wv][0];

    for (int s0 = 0; s0 < 512; s0 += 64) {
        // ---- S = qu . k^T (16 x 64) ----
        f32x4 S[4];
#pragma unroll
        for (int nb = 0; nb < 4; ++nb) S[nb] = (f32x4)0.f;
#pragma unroll
        for (int ks = 0; ks < 2; ++ks)
#pragma unroll
            for (int nb = 0; nb < 4; ++nb) {
                const bf16x8 bk = *(const bf16x8*)(kb + (size_t)(s0 + nb * 16 + ln) * 64 + ks * 32 + quad * 8);
                S[nb] = __builtin_amdgcn_mfma_f32_16x16x32_bf16(aqu[ks], bk, S[nb], 0, 0, 0);
            }
        // ---- C2 window = qv . p[jlo..jlo+80)^T (16 x 80) ----
        const int jlo = 496 - t0 + s0;
        f32x4 C2[5];
#pragma unroll
        for (int nb = 0; nb < 5; ++nb) C2[nb] = (f32x4)0.f;
#pragma unroll
        for (int ks = 0; ks < 2; ++ks)
#pragma unroll
            for (int nb = 0; nb < 5; ++nb) {
                const bf16x8 bp = *(const bf16x8*)(pp + (size_t)(jlo + nb * 16 + ln) * 64 + ks * 32 + quad * 8);
                C2[nb] = __builtin_amdgcn_mfma_f32_16x16x32_bf16(aqv[ks], bp, C2[nb], 0, 0, 0);
            }
#pragma unroll
        for (int nb = 0; nb < 5; ++nb)
#pragma unroll
            for (int r = 0; r < 4; ++r)
                c2w[(quad * 4 + r) * 80 + nb * 16 + ln] = f2bf_(C2[nb][r]);
        __syncthreads();

        // ---- S += shifted bd; clamp; row-max ----
        float sv[4][4];
        float rmax[4] = {-1e30f, -1e30f, -1e30f, -1e30f};
#pragma unroll
        for (int nb = 0; nb < 4; ++nb)
#pragma unroll
            for (int r = 0; r < 4; ++r) {
                const int tloc = quad * 4 + r;
                const int col = nb * 16 + ln + 15 - tloc;   // [0,78]
                const float bd = bf2f_(c2w[tloc * 80 + col]);
                const float s = clampd_(S[nb][r] + bd);
                sv[nb][r] = s;
                rmax[r] = fmaxf(rmax[r], s);
            }
#pragma unroll
        for (int off = 1; off < 16; off <<= 1)
#pragma unroll
            for (int r = 0; r < 4; ++r)
                rmax[r] = fmaxf(rmax[r], __shfl_xor(rmax[r], off, 64));

        // ---- online softmax update ----
        float alpha[4], rsum[4] = {0.f, 0.f, 0.f, 0.f};
#pragma unroll
        for (int r = 0; r < 4; ++r) {
            const float mn = fmaxf(m[r], rmax[r]);
            alpha[r] = __expf(m[r] - mn);
            m[r] = mn;
        }
#pragma unroll
        for (int nb = 0; nb < 4; ++nb)
#pragma unroll
            for (int r = 0; r < 4; ++r) {
                const float p = __expf(sv[nb][r] - m[r]);
                rsum[r] += p;
                pw[(quad * 4 + r) * 64 + nb * 16 + ln] = f2bf_(p);
            }
#pragma unroll
        for (int off = 1; off < 16; off <<= 1)
#pragma unroll
            for (int r = 0; r < 4; ++r)
                rsum[r] += __shfl_xor(rsum[r], off, 64);
#pragma unroll
        for (int r = 0; r < 4; ++r) l[r] = l[r] * alpha[r] + rsum[r];
#pragma unroll
        for (int nb = 0; nb < 4; ++nb)
#pragma unroll
            for (int r = 0; r < 4; ++r) O[nb][r] *= alpha[r];
        __syncthreads();

        // ---- O += P . V  (P A-frags from LDS; V^T B-frags from global) ----
#pragma unroll
        for (int ks = 0; ks < 2; ++ks) {
            const bf16x8 ap = *(const bf16x8*)&pw[ln * 64 + ks * 32 + quad * 8];
#pragma unroll
            for (int nb = 0; nb < 4; ++nb) {
                const bf16x8 bv = *(const bf16x8*)(vt + (size_t)(nb * 16 + ln) * 512 + s0 + ks * 32 + quad * 8);
                O[nb] = __builtin_amdgcn_mfma_f32_16x16x32_bf16(ap, bv, O[nb], 0, 0, 0);
            }
        }
    }

    // ---- epilogue: normalize and write ao (t,b,c) ----
    float inv[4];
#pragma unroll
    for (int r = 0; r < 4; ++r) inv[r] = 1.f / l[r];
#pragma unroll
    for (int nb = 0; nb < 4; ++nb)
#pragma unroll
        for (int r = 0; r < 4; ++r) {
            const int t = t0 + quad * 4 + r;
            const int d = nb * 16 + ln;
            aob[((size_t)t * B_SZ + b) * 512 + h * 64 + d] = f2bf_(O[nb][r] * inv[r]);
        }
}

// ---------------------------------------------------------------------------
// Conv-module pieces (bf16 chain, R7-proven)
// ---------------------------------------------------------------------------
__global__ __launch_bounds__(256) void glu_k(const u16* __restrict__ in, u16* __restrict__ out)
{
    const int i4 = (blockIdx.x * 256 + threadIdx.x) * 4;
    const int n = i4 >> 9, c = i4 & 511;
    const uint2 av = *(const uint2*)(in + (size_t)n * 1024 + c);
    const uint2 gv = *(const uint2*)(in + (size_t)n * 1024 + 512 + c);
    const u16* au = (const u16*)&av;
    const u16* gu = (const u16*)&gv;
    u16 o[4];
#pragma unroll
    for (int q = 0; q < 4; ++q) {
        const float a = bf2f_(au[q]), g = bf2f_(gu[q]);
        o[q] = f2bf_(a * sigmoidf_(g));
    }
    *(uint2*)(out + i4) = *(uint2*)o;
}

__global__ __launch_bounds__(256) void dwt_k(const float* __restrict__ w, float* __restrict__ wT)
{
    const int idx = blockIdx.x * 256 + threadIdx.x;
    if (idx >= 31 * 512) return;
    const int j = idx >> 9, c = idx & 511;
    wT[idx] = w[c * 31 + j];
}

__global__ __launch_bounds__(256) void dwconv_k(
    const u16* __restrict__ g, const float* __restrict__ wT,
    const float* __restrict__ bb, u16* __restrict__ out)
{
    const int idx = blockIdx.x * 256 + threadIdx.x;
    const int c = idx & 511;
    const int b = (idx >> 9) & 15;
    const int t0 = (idx >> 13) * 8;
    float wr[31];
#pragma unroll
    for (int j = 0; j < 31; ++j) wr[j] = wT[j * 512 + c];
    float win[38];
#pragma unroll
    for (int jj = 0; jj < 38; ++jj) {
        const int tt = t0 - 30 + jj;
        win[jj] = (tt >= 0) ? bf2f_(g[((size_t)tt * B_SZ + b) * 512 + c]) : 0.f;
    }
    const float bias = bb[c];
#pragma unroll
    for (int o = 0; o < 8; ++o) {
        float acc = bias;
#pragma unroll
        for (int j = 0; j < 31; ++j) acc += win[o + j] * wr[j];
        out[((size_t)(t0 + o) * B_SZ + b) * 512 + c] = f2bf_(dswishf_(acc));
    }
}

__global__ __launch_bounds__(256) void norm_k(float* __restrict__ x)
{
    const int row = blockIdx.x * 4 + (threadIdx.x >> 6);
    const int lane = threadIdx.x & 63;
    float* r = x + (size_t)row * 512;
    float v[8];
    float ss = 0.f;
#pragma unroll
    for (int j = 0; j < 8; ++j) { v[j] = r[lane + (j << 6)]; ss += v[j] * v[j]; }
#pragma unroll
    for (int o = 32; o > 0; o >>= 1) ss += __shfl_xor(ss, o, 64);
    const float scale = rsqrtf(ss * (1.f / 512.f) + EPS_BN);
#pragma unroll
    for (int j = 0; j < 8; ++j) r[lane + (j << 6)] = v[j] * scale;
}

// ---------------------------------------------------------------------------
extern "C" void kernel_launch(void* const* d_in, const int* in_sizes, int n_in,
                              void* d_out, int out_size, void* d_ws, size_t ws_size,
                              hipStream_t stream)
{
    const float* src   = (const float*)d_in[0];
    const float* pos   = (const float*)d_in[1];
    const float* fm_w1 = (const float*)d_in[2];
    const float* fm_b1 = (const float*)d_in[3];
    const float* fm_w2 = (const float*)d_in[4];
    const float* fm_b2 = (const float*)d_in[5];
    const float* f_w1  = (const float*)d_in[6];
    const float* f_b1  = (const float*)d_in[7];
    const float* f_w2  = (const float*)d_in[8];
    const float* f_b2  = (const float*)d_in[9];
    const float* ipw   = (const float*)d_in[10];
    const float* ipb   = (const float*)d_in[11];
    const float* opw   = (const float*)d_in[12];
    const float* opb   = (const float*)d_in[13];
    const float* lpw   = (const float*)d_in[14];
    const float* pbu   = (const float*)d_in[15];
    const float* pbv   = (const float*)d_in[16];
    const float* cpw1  = (const float*)d_in[17];
    const float* cpb1  = (const float*)d_in[18];
    const float* cdw   = (const float*)d_in[19];
    const float* cdb   = (const float*)d_in[20];
    const float* cpw2  = (const float*)d_in[21];
    const float* cpb2  = (const float*)d_in[22];

    float* x = (float*)d_out;              // running activation (8192 x 512) f32

    // ---- workspace layout (~133 MB) ----
    char* base = (char*)d_ws;
    u16*   wb    = (u16*)base;   base += 6291456ull * 2;   // 9 weights bf16
    u16*   src_b = (u16*)base;   base += 4194304ull * 2;
    u16*   pos_b = (u16*)base;   base += 524288ull * 2;    // 1024x512 padded
    u16*   xb    = (u16*)base;   base += 4194304ull * 2;
    u16*   hb    = (u16*)base;   base += 16777216ull * 2;  // FFN hidden / dwconv out
    u16*   aob   = (u16*)base;   base += 4194304ull * 2;
    u16*   qu_b  = (u16*)base;   base += 4194304ull * 2;
    u16*   qv_b  = (u16*)base;   base += 4194304ull * 2;
    u16*   k_b   = (u16*)base;   base += 4194304ull * 2;
    u16*   v_b   = (u16*)base;   base += 4194304ull * 2;
    u16*   vt_b  = (u16*)base;   base += 4194304ull * 2;
    u16*   p_b   = (u16*)base;   base += 524288ull * 2;    // [8][1024][64]
    float* wTd   = (float*)base; base += 15872ull * 4;
    u16*   pw1_o = (u16*)base;   base += 8388608ull * 2;   // conv pw1 out (8192x1024)
    u16*   glu_o = (u16*)base;   base += 4194304ull * 2;   // conv glu out (8192x512)

    u16* fm_w1b = wb;
    u16* fm_w2b = wb + 1048576;
    u16* f_w1b  = wb + 2097152;
    u16* f_w2b  = wb + 3145728;
    u16* ipwb   = wb + 4194304;
    u16* opwb   = wb + 4980736;
    u16* lpwb   = wb + 5242880;
    u16* cpw1b  = wb + 5505024;
    u16* cpw2b  = wb + 6029312;

    const dim3 blk(256);

    // 0) f32 -> bf16 conversions
    WPtrs wp = {{fm_w1, fm_w2, f_w1, f_w2, ipw, opw, lpw, cpw1, cpw2}};
    cvt_w_k<<<dim3(6291456 / 1024), blk, 0, stream>>>(wp, wb);
    cvt_k<<<dim3(4194304 / 1024), blk, 0, stream>>>(src, src_b);
    cvt_pos_k<<<dim3(524288 / 1024), blk, 0, stream>>>(pos, pos_b);
    dwt_k<<<dim3(62), blk, 0, stream>>>(cdw, wTd);

    // 1) macaron FFN: x = src + W2 @ dswish(W1 @ src)
    gemm_mfma<1, false, false, true><<<dim3(16, 64), blk, 0, stream>>>(
        src_b, fm_w1b, fm_b1, nullptr, nullptr, hb, NROWS, 512, DFF_);
    gemm_mfma<0, true, true, true><<<dim3(4, 64), blk, 0, stream>>>(
        hb, fm_w2b, fm_b2, src, x, xb, NROWS, DFF_, 512);

    // 2) qkv / pos projections with fused repack epilogues; V transpose
    gemm_fused<0><<<dim3(12, 64), blk, 0, stream>>>(
        xb, ipwb, ipb, pbu, pbv, qu_b, qv_b, k_b, v_b, nullptr, NROWS, 512, 1536);
    gemm_fused<1><<<dim3(4, 8), blk, 0, stream>>>(
        pos_b, lpwb, nullptr, nullptr, nullptr,
        nullptr, nullptr, nullptr, nullptr, p_b, 1024, 512, 512);
    vt_k<<<dim3(8, 128), blk, 0, stream>>>(v_b, vt_b);

    // 3) fused flash rel-pos attention (single launch, full batch)
    flash_attn<<<dim3(8, 128), blk, 0, stream>>>(qu_b, qv_b, k_b, vt_b, p_b, aob);

    // 4) out projection (residual into x)
    gemm_mfma<0, true, true, true><<<dim3(4, 64), blk, 0, stream>>>(
        aob, opwb, opb, x, x, xb, NROWS, 512, 512);

    // 5) conv module: pw1(bf16) -> GLU(bf16) -> dwconv(+dswish) -> pw2 (residual)
    gemm_mfma<0, false, false, true><<<dim3(8, 64), blk, 0, stream>>>(
        xb, cpw1b, cpb1, nullptr, nullptr, pw1_o, NROWS, 512, 1024);
    glu_k<<<dim3(NROWS * 512 / 1024), blk, 0, stream>>>(pw1_o, glu_o);
    dwconv_k<<<dim3(2048), blk, 0, stream>>>(glu_o, wTd, cdb, hb);
    gemm_mfma<0, true, true, true><<<dim3(4, 64), blk, 0, stream>>>(
        hb, cpw2b, cpb2, x, x, xb, NROWS, 512, 512);

    // 6) second FFN
    gemm_mfma<1, false, false, true><<<dim3(16, 64), blk, 0, stream>>>(
        xb, f_w1b, f_b1, nullptr, nullptr, hb, NROWS, 512, DFF_);
    gemm_mfma<0, true, true, false><<<dim3(4, 64), blk, 0, stream>>>(
        hb, f_w2b, f_b2, x, x, nullptr, NROWS, DFF_, 512);

    // 7) BasicNorm
    norm_k<<<dim3(NROWS / 4), blk, 0, stream>>>(x);
}